// Round 11
// baseline (12.976 us; speedup 1.0000x reference)
//
#include <hip/hip_runtime.h>
#include <hip/hip_bf16.h>

#define N_ENT 40943
#define DIM   128
#define NB    32
#define QPAD  136   // LDS row stride in bf16 elems (128+8): +4-bank shift/row, 16B aligned

typedef __attribute__((ext_vector_type(8))) short bfrag_t;
typedef __attribute__((ext_vector_type(4))) float f32x4_t;

__device__ inline short bf16_bits(float f) {
    __hip_bfloat16 h = __float2bfloat16(f);
    return *reinterpret_cast<short*>(&h);
}

// Fused kernel. score[b,e] = ||q_b||^2 + ||t_e||^2 - 2 q_b . t_e
// Each wave scores 32 entities (two 16-wide B-tiles reusing the same A-frags);
// t-loads issued inline after the barrier (round-8 ordering beat hoisting).
__global__ __launch_bounds__(256) void transe_fused(
    const int* __restrict__ heads,
    const int* __restrict__ rels,
    const float* __restrict__ ent_w,
    const float* __restrict__ rel_w,
    float* __restrict__ out)
{
    __shared__ unsigned short qbf[NB][QPAD];  // q rows as bf16
    __shared__ float qn[NB];                  // ||q_b||^2

    const int tid = threadIdx.x;

    // ---- prep: thread -> (batch b = tid>>3, 16-float chunk c = (tid&7)*16) ----
    {
        const int b = tid >> 3;
        const int c = (tid & 7) * 16;
        const int h = heads[b];
        const int r = rels[b];
        const float4* eh = (const float4*)(ent_w + (size_t)h * DIM + c);
        const float4* rr = (const float4*)(rel_w + (size_t)r * DIM + c);
        float part = 0.f;
        #pragma unroll
        for (int k = 0; k < 4; ++k) {
            float4 a = eh[k], bb = rr[k];
            float v0 = a.x + bb.x, v1 = a.y + bb.y, v2 = a.z + bb.z, v3 = a.w + bb.w;
            part = fmaf(v0, v0, fmaf(v1, v1, fmaf(v2, v2, fmaf(v3, v3, part))));
            short4 s;
            s.x = bf16_bits(v0); s.y = bf16_bits(v1);
            s.z = bf16_bits(v2); s.w = bf16_bits(v3);
            *(short4*)(&qbf[b][c + 4 * k]) = s;
        }
        part += __shfl_down(part, 4);
        part += __shfl_down(part, 2);
        part += __shfl_down(part, 1);
        if ((tid & 7) == 0) qn[b] = part;
    }
    __syncthreads();

    // ---- MFMA scoring: one wave per 32-entity tile ----
    const int lane = tid & 63;
    const int wid  = tid >> 6;
    const int e0   = (blockIdx.x * 4 + wid) * 32;

    const int er = lane & 15;            // A row (batch) and B col (entity-in-tile)
    const int kg = lane >> 4;            // k-group 0..3 (8 contiguous k each)
    const int erow0 = e0 + er;
    const int erow1 = e0 + 16 + er;
    const int eld0 = erow0 < N_ENT ? erow0 : N_ENT - 1;
    const int eld1 = erow1 < N_ENT ? erow1 : N_ENT - 1;

    // A fragments (q, bf16) from LDS: batch rows {er, er+16}
    bfrag_t a0[4], a1[4];
    #pragma unroll
    for (int kt = 0; kt < 4; ++kt) {
        a0[kt] = *(const bfrag_t*)(&qbf[er][8 * kg + 32 * kt]);
        a1[kt] = *(const bfrag_t*)(&qbf[er + 16][8 * kg + 32 * kt]);
    }

    // B fragments: two t-rows per lane, fp32 from global (each row used once),
    // convert to bf16, fold ||t||^2 partials.
    const float* tp0 = ent_w + (size_t)eld0 * DIM + 8 * kg;
    const float* tp1 = ent_w + (size_t)eld1 * DIM + 8 * kg;
    f32x4_t acc00 = {0.f,0.f,0.f,0.f}, acc01 = {0.f,0.f,0.f,0.f};
    f32x4_t acc10 = {0.f,0.f,0.f,0.f}, acc11 = {0.f,0.f,0.f,0.f};
    float tn0 = 0.f, tn1 = 0.f;
    #pragma unroll
    for (int kt = 0; kt < 4; ++kt) {
        f32x4_t u0 = *(const f32x4_t*)(tp0 + 32 * kt);
        f32x4_t u1 = *(const f32x4_t*)(tp0 + 32 * kt + 4);
        f32x4_t v0 = *(const f32x4_t*)(tp1 + 32 * kt);
        f32x4_t v1 = *(const f32x4_t*)(tp1 + 32 * kt + 4);
        bfrag_t bf0, bf1;
        #pragma unroll
        for (int j = 0; j < 4; ++j) {
            tn0 = fmaf(u0[j], u0[j], tn0);
            tn0 = fmaf(u1[j], u1[j], tn0);
            tn1 = fmaf(v0[j], v0[j], tn1);
            tn1 = fmaf(v1[j], v1[j], tn1);
            bf0[j]     = bf16_bits(u0[j]);
            bf0[j + 4] = bf16_bits(u1[j]);
            bf1[j]     = bf16_bits(v0[j]);
            bf1[j + 4] = bf16_bits(v1[j]);
        }
        acc00 = __builtin_amdgcn_mfma_f32_16x16x32_bf16(a0[kt], bf0, acc00, 0, 0, 0);
        acc01 = __builtin_amdgcn_mfma_f32_16x16x32_bf16(a1[kt], bf0, acc01, 0, 0, 0);
        acc10 = __builtin_amdgcn_mfma_f32_16x16x32_bf16(a0[kt], bf1, acc10, 0, 0, 0);
        acc11 = __builtin_amdgcn_mfma_f32_16x16x32_bf16(a1[kt], bf1, acc11, 0, 0, 0);
    }
    // lanes {er, er+16, er+32, er+48} hold complementary k-ranges of the same t-row
    tn0 += __shfl_xor(tn0, 16);
    tn0 += __shfl_xor(tn0, 32);
    tn1 += __shfl_xor(tn1, 16);
    tn1 += __shfl_xor(tn1, 32);

    #pragma unroll
    for (int r = 0; r < 4; ++r) {
        const int b0 = 4 * kg + r;       // C/D: row = 4*(lane>>4)+reg, col = lane&15
        if (erow0 < N_ENT) {
            out[(size_t)b0        * N_ENT + erow0] = qn[b0]      + tn0 - 2.f * acc00[r];
            out[(size_t)(b0 + 16) * N_ENT + erow0] = qn[b0 + 16] + tn0 - 2.f * acc01[r];
        }
        if (erow1 < N_ENT) {
            out[(size_t)b0        * N_ENT + erow1] = qn[b0]      + tn1 - 2.f * acc10[r];
            out[(size_t)(b0 + 16) * N_ENT + erow1] = qn[b0 + 16] + tn1 - 2.f * acc11[r];
        }
    }
}

extern "C" void kernel_launch(void* const* d_in, const int* in_sizes, int n_in,
                              void* d_out, int out_size, void* d_ws, size_t ws_size,
                              hipStream_t stream) {
    const int*   heads = (const int*)d_in[0];
    const int*   rels  = (const int*)d_in[1];
    const float* ent_w = (const float*)d_in[2];
    const float* rel_w = (const float*)d_in[3];
    float* out = (float*)d_out;

    const int grid = (N_ENT + 127) / 128;  // 4 waves/block, 32 entities/wave -> 320 blocks
    transe_fused<<<grid, 256, 0, stream>>>(heads, rels, ent_w, rel_w, out);
}

// Round 12
// 11.901 us; speedup vs baseline: 1.0904x; 1.0904x over previous
//
#include <hip/hip_runtime.h>
#include <hip/hip_bf16.h>

#define N_ENT 40943
#define DIM   128
#define NB    32
#define QPAD  136   // LDS row stride in bf16 elems (128+8): +4-bank shift/row, 16B aligned

typedef __attribute__((ext_vector_type(8))) short bfrag_t;
typedef __attribute__((ext_vector_type(4))) float f32x4_t;

__device__ inline short bf16_bits(float f) {
    __hip_bfloat16 h = __float2bfloat16(f);
    return *reinterpret_cast<short*>(&h);
}

// Round-8 configuration (best measured: 11.91 us).
// Single fused kernel: per-block q-prep + MFMA scoring, 16 entities/wave,
// 640 blocks, t-loads inline after the barrier.
// score[b,e] = ||q_b||^2 + ||t_e||^2 - 2 q_b . t_e
__global__ __launch_bounds__(256) void transe_fused(
    const int* __restrict__ heads,
    const int* __restrict__ rels,
    const float* __restrict__ ent_w,
    const float* __restrict__ rel_w,
    float* __restrict__ out)
{
    __shared__ unsigned short qbf[NB][QPAD];  // q rows as bf16
    __shared__ float qn[NB];                  // ||q_b||^2

    const int tid = threadIdx.x;

    // ---- prep: thread -> (batch b = tid>>3, 16-float chunk c = (tid&7)*16) ----
    {
        const int b = tid >> 3;
        const int c = (tid & 7) * 16;
        const int h = heads[b];
        const int r = rels[b];
        const float4* eh = (const float4*)(ent_w + (size_t)h * DIM + c);
        const float4* rr = (const float4*)(rel_w + (size_t)r * DIM + c);
        float part = 0.f;
        #pragma unroll
        for (int k = 0; k < 4; ++k) {
            float4 a = eh[k], bb = rr[k];
            float v0 = a.x + bb.x, v1 = a.y + bb.y, v2 = a.z + bb.z, v3 = a.w + bb.w;
            part = fmaf(v0, v0, fmaf(v1, v1, fmaf(v2, v2, fmaf(v3, v3, part))));
            short4 s;
            s.x = bf16_bits(v0); s.y = bf16_bits(v1);
            s.z = bf16_bits(v2); s.w = bf16_bits(v3);
            *(short4*)(&qbf[b][c + 4 * k]) = s;
        }
        part += __shfl_down(part, 4);
        part += __shfl_down(part, 2);
        part += __shfl_down(part, 1);
        if ((tid & 7) == 0) qn[b] = part;
    }
    __syncthreads();

    // ---- MFMA scoring: one wave per 16-entity tile ----
    const int lane = tid & 63;
    const int wid  = tid >> 6;
    const int e0   = (blockIdx.x * 4 + wid) * 16;

    const int er   = lane & 15;          // entity-in-tile == q row-in-tile
    const int kg   = lane >> 4;          // k-group 0..3 (8 contiguous k each)
    const int erow = e0 + er;
    const int eld  = erow < N_ENT ? erow : N_ENT - 1;   // clamp loads, mask stores

    // A fragments (q, bf16) from LDS: rows {er, er+16}
    bfrag_t a0[4], a1[4];
    #pragma unroll
    for (int kt = 0; kt < 4; ++kt) {
        a0[kt] = *(const bfrag_t*)(&qbf[er][8 * kg + 32 * kt]);
        a1[kt] = *(const bfrag_t*)(&qbf[er + 16][8 * kg + 32 * kt]);
    }

    // B fragments: t-row fp32 straight from global (each row used once),
    // convert to bf16, fold ||t||^2 partial from the same values.
    const float* tp = ent_w + (size_t)eld * DIM + 8 * kg;
    f32x4_t acc0 = {0.f, 0.f, 0.f, 0.f};
    f32x4_t acc1 = {0.f, 0.f, 0.f, 0.f};
    float tn = 0.f;
    #pragma unroll
    for (int kt = 0; kt < 4; ++kt) {
        f32x4_t t0 = *(const f32x4_t*)(tp + 32 * kt);
        f32x4_t t1 = *(const f32x4_t*)(tp + 32 * kt + 4);
        bfrag_t bf;
        #pragma unroll
        for (int j = 0; j < 4; ++j) {
            tn = fmaf(t0[j], t0[j], tn);
            tn = fmaf(t1[j], t1[j], tn);
            bf[j]     = bf16_bits(t0[j]);
            bf[j + 4] = bf16_bits(t1[j]);
        }
        acc0 = __builtin_amdgcn_mfma_f32_16x16x32_bf16(a0[kt], bf, acc0, 0, 0, 0);
        acc1 = __builtin_amdgcn_mfma_f32_16x16x32_bf16(a1[kt], bf, acc1, 0, 0, 0);
    }
    // lanes {er, er+16, er+32, er+48} hold complementary k-ranges of the same t-row
    tn += __shfl_xor(tn, 16);
    tn += __shfl_xor(tn, 32);

    if (erow < N_ENT) {
        #pragma unroll
        for (int r = 0; r < 4; ++r) {
            const int b0 = 4 * kg + r;   // C/D: row = 4*(lane>>4)+reg, col = lane&15
            out[(size_t)b0        * N_ENT + erow] = qn[b0]      + tn - 2.f * acc0[r];
            out[(size_t)(b0 + 16) * N_ENT + erow] = qn[b0 + 16] + tn - 2.f * acc1[r];
        }
    }
}

extern "C" void kernel_launch(void* const* d_in, const int* in_sizes, int n_in,
                              void* d_out, int out_size, void* d_ws, size_t ws_size,
                              hipStream_t stream) {
    const int*   heads = (const int*)d_in[0];
    const int*   rels  = (const int*)d_in[1];
    const float* ent_w = (const float*)d_in[2];
    const float* rel_w = (const float*)d_in[3];
    float* out = (float*)d_out;

    const int grid = (N_ENT + 63) / 64;   // 4 waves/block, 16 entities/wave -> 640 blocks
    transe_fused<<<grid, 256, 0, stream>>>(heads, rels, ent_w, rel_w, out);
}